// Round 11
// baseline (33.240 us; speedup 1.0000x reference)
//
#include <hip/hip_runtime.h>
#include <math.h>

__device__ __forceinline__ float frcp(float x) { return __builtin_amdgcn_rcpf(x); }

// Exact area of CCW polygon ∩ axis-aligned box [-hw,hw]x[-hh,hh] via the
// per-edge coverage identity (validated R5-R10, absmax 0 vs jax reference):
//   Area = sum_e sigma_e * ( ∫ clamp(y_e(x), Y0, Y1) dx - Y0 * w_e ),
// integral over the edge's x-range clipped to the box's x-slab.
__device__ __forceinline__ float edge_area(float px, float py, float qx, float qy,
                                           float hw, float hh) {
    const float Y0 = -hh, Y1 = hh;
    float dx = qx - px, dy = qy - py;
    float lo = fmaxf(fminf(px, qx), -hw);
    float hi = fminf(fmaxf(px, qx),  hw);
    float w  = hi - lo;
    float dys = (fabsf(dy) > 1e-20f) ? dy : ((dy >= 0.f) ? 1e-20f : -1e-20f);
    float dxs = (fabsf(dx) > 1e-20f) ? dx : ((dx >= 0.f) ? 1e-20f : -1e-20f);
    float xdy = dx * frcp(dys);
    float m   = dy * frcp(dxs);
    float xa = fmaf(Y0 - py, xdy, px);
    float xb = fmaf(Y1 - py, xdy, px);
    float s0 = fminf(xa, xb), s1 = fmaxf(xa, xb);
    float u0 = fminf(fmaxf(s0, lo), hi);
    float u1 = fminf(fmaxf(s1, lo), hi);
    float yu0 = fmaf(m, u0 - px, py);
    float yu1 = fmaf(m, u1 - px, py);
    yu0 = fminf(fmaxf(yu0, Y0), Y1);
    yu1 = fminf(fmaxf(yu1, Y0), Y1);
    bool mpos = (dy >= 0.f) == (dx >= 0.f);
    float YL = mpos ? Y0 : Y1;
    float YR = mpos ? Y1 : Y0;
    float integral = YL * (u0 - lo)
                   + 0.5f * (yu0 + yu1) * (u1 - u0)
                   + YR * (hi - u1);
    float contrib = integral - Y0 * w;
    float res = (dx > 0.f) ? -contrib : contrib;
    return (w > 0.f) ? res : 0.f;
}

// one element: b1/b2 are 7 floats each -> 1 - iou3d
__device__ __forceinline__ float elem_loss(const float b1[7], const float b2[7]) {
    float x1 = b1[0], y1 = b1[1], z1 = b1[2], w1 = b1[3], h1 = b1[4], dz1 = b1[5], a1 = b1[6];
    float x2 = b2[0], y2 = b2[1], z2 = b2[2], w2 = b2[3], h2 = b2[4], dz2 = b2[5], a2 = b2[6];

    float zo = fmaxf(fminf(z1 + 0.5f * dz1, z2 + 0.5f * dz2)
                   - fmaxf(z1 - 0.5f * dz1, z2 - 0.5f * dz2), 0.0f);
    float vol1 = w1 * h1 * dz1;
    float vol2 = w2 * h2 * dz2;

    float sa = __sinf(a2), ca = __cosf(a2);
    float dxc = x1 - x2, dyc = y1 - y2;
    float tx =  dxc * ca + dyc * sa;
    float ty = -dxc * sa + dyc * ca;
    float ad = a1 - a2;
    float sd = __sinf(ad), cd = __cosf(ad);
    float hw1 = 0.5f * w1, hh1 = 0.5f * h1;
    float hw2 = 0.5f * w2, hh2 = 0.5f * h2;
    float ex = hw1 * cd, ey = hw1 * sd;
    float fx = -hh1 * sd, fy = hh1 * cd;
    float q0x = tx + ex + fx, q0y = ty + ey + fy;
    float q1x = tx - ex + fx, q1y = ty - ey + fy;
    float q2x = tx - ex - fx, q2y = ty - ey - fy;
    float q3x = tx + ex - fx, q3y = ty + ey - fy;

    float area = edge_area(q0x, q0y, q1x, q1y, hw2, hh2)
               + edge_area(q1x, q1y, q2x, q2y, hw2, hh2)
               + edge_area(q2x, q2y, q3x, q3y, hw2, hh2)
               + edge_area(q3x, q3y, q0x, q0y, hw2, hh2);
    area = fabsf(area);

    float inter3d = area * zo;
    float union3d = vol1 + vol2 - inter3d;
    return 1.0f - inter3d * frcp(union3d);   // fast rcp: ~1e-7 rel err vs 2e-2 threshold
}

#define WAVES 4        // waves per 256-thread block
#define TILES 4        // tiles per wave (software pipelined)
#define TILE_ELEMS 128 // elems per tile (2 per lane)

// NOTE: assumes N even (N=1e6 here), so N*7/2 is exact in float2 units.

__global__ __launch_bounds__(256) void iou3d_fused_kernel(
    const float* __restrict__ pred, const float* __restrict__ target,
    float* __restrict__ partial, unsigned* __restrict__ counter,
    float* __restrict__ out, int N, int nblocks)
{
    __shared__ float lds[WAVES][1792];   // per-wave: 896 f32 pred + 896 f32 target
    const int lane = threadIdx.x & 63;
    const int wid  = threadIdx.x >> 6;
    const int gw   = blockIdx.x * WAVES + wid;     // global wave id
    const int tile0 = gw * TILES;
    const int totF2 = (N * 7) >> 1;                // float2 count (N even)

    const float2* pred2 = (const float2*)pred;
    const float2* targ2 = (const float2*)target;
    float2* ldsP = (float2*)&lds[wid][0];
    float2* ldsT = (float2*)&lds[wid][896];

    float2 pa[7], pb[7];

    // guarded/unguarded prefetch of tile TIDX into pa/pb
    #define PREFETCH(TIDX) do { \
        const int f2b_ = (TIDX) * 448; \
        if (((TIDX) + 1) * TILE_ELEMS <= N) { \
            _Pragma("unroll") \
            for (int k = 0; k < 7; k++) { \
                int idx = f2b_ + k * 64 + lane; \
                pa[k] = pred2[idx]; pb[k] = targ2[idx]; \
            } \
        } else { \
            _Pragma("unroll") \
            for (int k = 0; k < 7; k++) { \
                int idx = f2b_ + k * 64 + lane; \
                bool ok = idx < totF2; \
                pa[k] = ok ? pred2[idx] : make_float2(0.f, 0.f); \
                pb[k] = ok ? targ2[idx] : make_float2(0.f, 0.f); \
            } \
        } \
    } while (0)

    float val = 0.f;
    PREFETCH(tile0);

    // pipelined tile loop: ds_write(cur) -> prefetch(next) -> ds_read -> compute.
    // Wave-private LDS buffer + in-order same-wave DS ops: no barriers needed;
    // next tile's global loads fly during current tile's compute.
    #pragma unroll 1
    for (int t = 0; t < TILES; t++) {
        #pragma unroll
        for (int k = 0; k < 7; k++) {
            ldsP[k * 64 + lane] = pa[k];
            ldsT[k * 64 + lane] = pb[k];
        }
        if (t + 1 < TILES) PREFETCH(tile0 + t + 1);
        float af[14], bf[14];
        #pragma unroll
        for (int j = 0; j < 7; j++) {
            float2 va = ldsP[7 * lane + j];
            float2 vb = ldsT[7 * lane + j];
            af[2 * j] = va.x; af[2 * j + 1] = va.y;
            bf[2 * j] = vb.x; bf[2 * j + 1] = vb.y;
        }
        int e0 = (tile0 + t) * TILE_ELEMS + 2 * lane;
        if (e0 < N)     val += elem_loss(&af[0], &bf[0]);
        if (e0 + 1 < N) val += elem_loss(&af[7], &bf[7]);
    }
    #undef PREFETCH

    // ---- block reduction -> partial, then last-block finalize ----
    #pragma unroll
    for (int off = 32; off > 0; off >>= 1)
        val += __shfl_down(val, off, 64);
    __shared__ float wsum[WAVES];
    __shared__ bool last;
    if (lane == 0) wsum[wid] = val;
    __syncthreads();
    if (threadIdx.x == 0) {
        float s = wsum[0] + wsum[1] + wsum[2] + wsum[3];
        partial[blockIdx.x] = s;
        __threadfence();                       // partial visible before counter inc
        unsigned old = atomicAdd(counter, 1u);
        last = (old == (unsigned)(nblocks - 1));
    }
    __syncthreads();
    if (last) {
        __threadfence();                       // acquire: other blocks' partials
        float s = 0.f;
        for (int i = threadIdx.x; i < nblocks; i += 256) s += partial[i];
        #pragma unroll
        for (int off = 32; off > 0; off >>= 1)
            s += __shfl_down(s, off, 64);
        if (lane == 0) wsum[wid] = s;
        __syncthreads();
        if (threadIdx.x == 0) {
            float tsum = wsum[0] + wsum[1] + wsum[2] + wsum[3];
            out[0] = (float)((double)tsum / (double)N);
        }
    }
}

extern "C" void kernel_launch(void* const* d_in, const int* in_sizes, int n_in,
                              void* d_out, int out_size, void* d_ws, size_t ws_size,
                              hipStream_t stream) {
    const float* pred   = (const float*)d_in[0];
    const float* target = (const float*)d_in[1];
    int N = in_sizes[0] / 7;

    float*    partial = (float*)d_ws;
    unsigned* counter = (unsigned*)((char*)d_ws + (1 << 20));  // 1 MB in: clear of partials

    long tiles = ((long)N + TILE_ELEMS - 1) / TILE_ELEMS;
    long waves = (tiles + TILES - 1) / TILES;
    int grid = (int)((waves + WAVES - 1) / WAVES);

    hipMemsetAsync(counter, 0, sizeof(unsigned), stream);
    iou3d_fused_kernel<<<grid, 256, 0, stream>>>(pred, target, partial, counter,
                                                 (float*)d_out, N, grid);
}

// Round 13
// 33.238 us; speedup vs baseline: 1.0001x; 1.0001x over previous
//
#include <hip/hip_runtime.h>
#include <math.h>

__device__ __forceinline__ float frcp(float x) { return __builtin_amdgcn_rcpf(x); }

// Exact area of CCW polygon ∩ axis-aligned box [-hw,hw]x[-hh,hh] via the
// per-edge coverage identity (validated R5-R11, absmax 0 vs jax reference):
//   Area = sum_e sigma_e * ( ∫ clamp(y_e(x), Y0, Y1) dx - Y0 * w_e ),
// integral over the edge's x-range clipped to the box's x-slab.
__device__ __forceinline__ float edge_area(float px, float py, float qx, float qy,
                                           float hw, float hh) {
    const float Y0 = -hh, Y1 = hh;
    float dx = qx - px, dy = qy - py;
    float lo = fmaxf(fminf(px, qx), -hw);
    float hi = fminf(fmaxf(px, qx),  hw);
    float w  = hi - lo;
    float dys = (fabsf(dy) > 1e-20f) ? dy : ((dy >= 0.f) ? 1e-20f : -1e-20f);
    float dxs = (fabsf(dx) > 1e-20f) ? dx : ((dx >= 0.f) ? 1e-20f : -1e-20f);
    float xdy = dx * frcp(dys);
    float m   = dy * frcp(dxs);
    float xa = fmaf(Y0 - py, xdy, px);
    float xb = fmaf(Y1 - py, xdy, px);
    float s0 = fminf(xa, xb), s1 = fmaxf(xa, xb);
    float u0 = fminf(fmaxf(s0, lo), hi);
    float u1 = fminf(fmaxf(s1, lo), hi);
    float yu0 = fmaf(m, u0 - px, py);
    float yu1 = fmaf(m, u1 - px, py);
    yu0 = fminf(fmaxf(yu0, Y0), Y1);
    yu1 = fminf(fmaxf(yu1, Y0), Y1);
    bool mpos = (dy >= 0.f) == (dx >= 0.f);
    float YL = mpos ? Y0 : Y1;
    float YR = mpos ? Y1 : Y0;
    float integral = YL * (u0 - lo)
                   + 0.5f * (yu0 + yu1) * (u1 - u0)
                   + YR * (hi - u1);
    float contrib = integral - Y0 * w;
    float res = (dx > 0.f) ? -contrib : contrib;
    return (w > 0.f) ? res : 0.f;
}

// one element: b1/b2 are 7 floats each -> 1 - iou3d
__device__ __forceinline__ float elem_loss(const float b1[7], const float b2[7]) {
    float x1 = b1[0], y1 = b1[1], z1 = b1[2], w1 = b1[3], h1 = b1[4], dz1 = b1[5], a1 = b1[6];
    float x2 = b2[0], y2 = b2[1], z2 = b2[2], w2 = b2[3], h2 = b2[4], dz2 = b2[5], a2 = b2[6];

    float zo = fmaxf(fminf(z1 + 0.5f * dz1, z2 + 0.5f * dz2)
                   - fmaxf(z1 - 0.5f * dz1, z2 - 0.5f * dz2), 0.0f);
    float vol1 = w1 * h1 * dz1;
    float vol2 = w2 * h2 * dz2;

    float sa = __sinf(a2), ca = __cosf(a2);
    float dxc = x1 - x2, dyc = y1 - y2;
    float tx =  dxc * ca + dyc * sa;
    float ty = -dxc * sa + dyc * ca;
    float ad = a1 - a2;
    float sd = __sinf(ad), cd = __cosf(ad);
    float hw1 = 0.5f * w1, hh1 = 0.5f * h1;
    float hw2 = 0.5f * w2, hh2 = 0.5f * h2;
    float ex = hw1 * cd, ey = hw1 * sd;
    float fx = -hh1 * sd, fy = hh1 * cd;
    float q0x = tx + ex + fx, q0y = ty + ey + fy;
    float q1x = tx - ex + fx, q1y = ty - ey + fy;
    float q2x = tx - ex - fx, q2y = ty - ey - fy;
    float q3x = tx + ex - fx, q3y = ty + ey - fy;

    float area = edge_area(q0x, q0y, q1x, q1y, hw2, hh2)
               + edge_area(q1x, q1y, q2x, q2y, hw2, hh2)
               + edge_area(q2x, q2y, q3x, q3y, hw2, hh2)
               + edge_area(q3x, q3y, q0x, q0y, hw2, hh2);
    area = fabsf(area);

    float inter3d = area * zo;
    float union3d = vol1 + vol2 - inter3d;
    return 1.0f - inter3d * frcp(union3d);   // fast rcp: ~1e-7 rel err vs 2e-2 threshold
}

#define WAVES 4        // waves per 256-thread block
#define TILES 4        // tiles per wave (software pipelined)
#define TILE_ELEMS 128 // elems per tile (2 per lane)

// NOTE: assumes N even (N=1e6 here), so N*7/2 is exact in float2 units.

// Node 1: 1-thread counter zero. A kernel node is ~2 us; a fill node was
// measured ~13 us (R11 regression) -- never use memset for a 4B counter.
__global__ void zero_counter_kernel(unsigned* __restrict__ counter) {
    *counter = 0u;
}

__global__ __launch_bounds__(256) void iou3d_fused_kernel(
    const float* __restrict__ pred, const float* __restrict__ target,
    float* __restrict__ partial, unsigned* __restrict__ counter,
    float* __restrict__ out, int N, int nblocks)
{
    __shared__ float lds[WAVES][1792];   // per-wave: 896 f32 pred + 896 f32 target
    const int lane = threadIdx.x & 63;
    const int wid  = threadIdx.x >> 6;
    const int gw   = blockIdx.x * WAVES + wid;     // global wave id
    const int tile0 = gw * TILES;
    const int totF2 = (N * 7) >> 1;                // float2 count (N even)

    const float2* pred2 = (const float2*)pred;
    const float2* targ2 = (const float2*)target;
    float2* ldsP = (float2*)&lds[wid][0];
    float2* ldsT = (float2*)&lds[wid][896];

    float2 pa[7], pb[7];

    // guarded/unguarded prefetch of tile TIDX into pa/pb
    #define PREFETCH(TIDX) do { \
        const int f2b_ = (TIDX) * 448; \
        if (((TIDX) + 1) * TILE_ELEMS <= N) { \
            _Pragma("unroll") \
            for (int k = 0; k < 7; k++) { \
                int idx = f2b_ + k * 64 + lane; \
                pa[k] = pred2[idx]; pb[k] = targ2[idx]; \
            } \
        } else { \
            _Pragma("unroll") \
            for (int k = 0; k < 7; k++) { \
                int idx = f2b_ + k * 64 + lane; \
                bool ok = idx < totF2; \
                pa[k] = ok ? pred2[idx] : make_float2(0.f, 0.f); \
                pb[k] = ok ? targ2[idx] : make_float2(0.f, 0.f); \
            } \
        } \
    } while (0)

    float val = 0.f;
    PREFETCH(tile0);

    // pipelined tile loop: ds_write(cur) -> prefetch(next) -> ds_read -> compute.
    // Wave-private LDS buffer + in-order same-wave DS ops: no barriers needed;
    // next tile's global loads fly during current tile's compute.
    #pragma unroll 1
    for (int t = 0; t < TILES; t++) {
        #pragma unroll
        for (int k = 0; k < 7; k++) {
            ldsP[k * 64 + lane] = pa[k];
            ldsT[k * 64 + lane] = pb[k];
        }
        if (t + 1 < TILES) PREFETCH(tile0 + t + 1);
        float af[14], bf[14];
        #pragma unroll
        for (int j = 0; j < 7; j++) {
            float2 va = ldsP[7 * lane + j];
            float2 vb = ldsT[7 * lane + j];
            af[2 * j] = va.x; af[2 * j + 1] = va.y;
            bf[2 * j] = vb.x; bf[2 * j + 1] = vb.y;
        }
        int e0 = (tile0 + t) * TILE_ELEMS + 2 * lane;
        if (e0 < N)     val += elem_loss(&af[0], &bf[0]);
        if (e0 + 1 < N) val += elem_loss(&af[7], &bf[7]);
    }
    #undef PREFETCH

    // ---- block reduction -> partial, then last-ARRIVER finalize ----
    // counter is zeroed by the preceding kernel node every call, so
    // old == nblocks-1 identifies the true last arriver (all partials
    // written and fenced before its increment). Finalizer self-resets the
    // counter (no race: every block has already incremented this call).
    #pragma unroll
    for (int off = 32; off > 0; off >>= 1)
        val += __shfl_down(val, off, 64);
    __shared__ float wsum[WAVES];
    __shared__ bool last;
    if (lane == 0) wsum[wid] = val;
    __syncthreads();
    if (threadIdx.x == 0) {
        float s = wsum[0] + wsum[1] + wsum[2] + wsum[3];
        partial[blockIdx.x] = s;
        __threadfence();                       // partial visible before counter inc
        unsigned old = atomicAdd(counter, 1u);
        last = (old == (unsigned)(nblocks - 1));
    }
    __syncthreads();
    if (last) {
        __threadfence();                       // acquire: other blocks' partials
        float s = 0.f;
        for (int i = threadIdx.x; i < nblocks; i += 256) s += partial[i];
        #pragma unroll
        for (int off = 32; off > 0; off >>= 1)
            s += __shfl_down(s, off, 64);
        if (lane == 0) wsum[wid] = s;
        __syncthreads();
        if (threadIdx.x == 0) {
            float tsum = wsum[0] + wsum[1] + wsum[2] + wsum[3];
            out[0] = (float)((double)tsum / (double)N);
            __threadfence();
            *counter = 0u;                     // idempotent self-reset
        }
    }
}

extern "C" void kernel_launch(void* const* d_in, const int* in_sizes, int n_in,
                              void* d_out, int out_size, void* d_ws, size_t ws_size,
                              hipStream_t stream) {
    const float* pred   = (const float*)d_in[0];
    const float* target = (const float*)d_in[1];
    int N = in_sizes[0] / 7;

    float*    partial = (float*)d_ws;
    unsigned* counter = (unsigned*)((char*)d_ws + (1 << 20));  // 1 MB in: clear of partials

    long tiles = ((long)N + TILE_ELEMS - 1) / TILE_ELEMS;
    long waves = (tiles + TILES - 1) / TILES;
    int grid = (int)((waves + WAVES - 1) / WAVES);

    zero_counter_kernel<<<1, 1, 0, stream>>>(counter);
    iou3d_fused_kernel<<<grid, 256, 0, stream>>>(pred, target, partial, counter,
                                                 (float*)d_out, N, grid);
}

// Round 14
// 19.008 us; speedup vs baseline: 1.7487x; 1.7486x over previous
//
#include <hip/hip_runtime.h>
#include <math.h>

__device__ __forceinline__ float frcp(float x) { return __builtin_amdgcn_rcpf(x); }

// Exact area of CCW polygon ∩ axis-aligned box [-hw,hw]x[-hh,hh] via the
// per-edge coverage identity (validated R5-R13, absmax 0 vs jax reference):
//   Area = sum_e sigma_e * ( ∫ clamp(y_e(x), Y0, Y1) dx - Y0 * w_e ),
// integral over the edge's x-range clipped to the box's x-slab.
__device__ __forceinline__ float edge_area(float px, float py, float qx, float qy,
                                           float hw, float hh) {
    const float Y0 = -hh, Y1 = hh;
    float dx = qx - px, dy = qy - py;
    float lo = fmaxf(fminf(px, qx), -hw);
    float hi = fminf(fmaxf(px, qx),  hw);
    float w  = hi - lo;
    float dys = (fabsf(dy) > 1e-20f) ? dy : ((dy >= 0.f) ? 1e-20f : -1e-20f);
    float dxs = (fabsf(dx) > 1e-20f) ? dx : ((dx >= 0.f) ? 1e-20f : -1e-20f);
    float xdy = dx * frcp(dys);
    float m   = dy * frcp(dxs);
    float xa = fmaf(Y0 - py, xdy, px);
    float xb = fmaf(Y1 - py, xdy, px);
    float s0 = fminf(xa, xb), s1 = fmaxf(xa, xb);
    float u0 = fminf(fmaxf(s0, lo), hi);
    float u1 = fminf(fmaxf(s1, lo), hi);
    float yu0 = fmaf(m, u0 - px, py);
    float yu1 = fmaf(m, u1 - px, py);
    yu0 = fminf(fmaxf(yu0, Y0), Y1);
    yu1 = fminf(fmaxf(yu1, Y0), Y1);
    bool mpos = (dy >= 0.f) == (dx >= 0.f);
    float YL = mpos ? Y0 : Y1;
    float YR = mpos ? Y1 : Y0;
    float integral = YL * (u0 - lo)
                   + 0.5f * (yu0 + yu1) * (u1 - u0)
                   + YR * (hi - u1);
    float contrib = integral - Y0 * w;
    float res = (dx > 0.f) ? -contrib : contrib;
    return (w > 0.f) ? res : 0.f;
}

// one element: b1/b2 are 7 floats each -> 1 - iou3d
__device__ __forceinline__ float elem_loss(const float b1[7], const float b2[7]) {
    float x1 = b1[0], y1 = b1[1], z1 = b1[2], w1 = b1[3], h1 = b1[4], dz1 = b1[5], a1 = b1[6];
    float x2 = b2[0], y2 = b2[1], z2 = b2[2], w2 = b2[3], h2 = b2[4], dz2 = b2[5], a2 = b2[6];

    float zo = fmaxf(fminf(z1 + 0.5f * dz1, z2 + 0.5f * dz2)
                   - fmaxf(z1 - 0.5f * dz1, z2 - 0.5f * dz2), 0.0f);
    float vol1 = w1 * h1 * dz1;
    float vol2 = w2 * h2 * dz2;

    float sa = __sinf(a2), ca = __cosf(a2);
    float dxc = x1 - x2, dyc = y1 - y2;
    float tx =  dxc * ca + dyc * sa;
    float ty = -dxc * sa + dyc * ca;
    float ad = a1 - a2;
    float sd = __sinf(ad), cd = __cosf(ad);
    float hw1 = 0.5f * w1, hh1 = 0.5f * h1;
    float hw2 = 0.5f * w2, hh2 = 0.5f * h2;
    float ex = hw1 * cd, ey = hw1 * sd;
    float fx = -hh1 * sd, fy = hh1 * cd;
    float q0x = tx + ex + fx, q0y = ty + ey + fy;
    float q1x = tx - ex + fx, q1y = ty - ey + fy;
    float q2x = tx - ex - fx, q2y = ty - ey - fy;
    float q3x = tx + ex - fx, q3y = ty + ey - fy;

    float area = edge_area(q0x, q0y, q1x, q1y, hw2, hh2)
               + edge_area(q1x, q1y, q2x, q2y, hw2, hh2)
               + edge_area(q2x, q2y, q3x, q3y, hw2, hh2)
               + edge_area(q3x, q3y, q0x, q0y, hw2, hh2);
    area = fabsf(area);

    float inter3d = area * zo;
    float union3d = vol1 + vol2 - inter3d;
    return 1.0f - inter3d * frcp(union3d);   // fast rcp: ~1e-7 rel err vs 2e-2 threshold
}

#define WAVES 4        // waves per 256-thread block
#define TILES 4        // tiles per wave (software pipelined)
#define TILE_ELEMS 128 // elems per tile (2 per lane)

// NOTE: assumes N even (N=1e6 here), so N*7/2 is exact in float2 units.

__global__ __launch_bounds__(256) void iou3d_loss_kernel(
    const float* __restrict__ pred, const float* __restrict__ target,
    float* __restrict__ partial, int N)
{
    __shared__ float lds[WAVES][1792];   // per-wave: 896 f32 pred + 896 f32 target
    const int lane = threadIdx.x & 63;
    const int wid  = threadIdx.x >> 6;
    const int gw   = blockIdx.x * WAVES + wid;     // global wave id
    const int tile0 = gw * TILES;
    const int totF2 = (N * 7) >> 1;                // float2 count (N even)

    const float2* pred2 = (const float2*)pred;
    const float2* targ2 = (const float2*)target;
    float2* ldsP = (float2*)&lds[wid][0];
    float2* ldsT = (float2*)&lds[wid][896];

    float2 pa[7], pb[7];

    // guarded/unguarded prefetch of tile TIDX into pa/pb
    #define PREFETCH(TIDX) do { \
        const int f2b_ = (TIDX) * 448; \
        if (((TIDX) + 1) * TILE_ELEMS <= N) { \
            _Pragma("unroll") \
            for (int k = 0; k < 7; k++) { \
                int idx = f2b_ + k * 64 + lane; \
                pa[k] = pred2[idx]; pb[k] = targ2[idx]; \
            } \
        } else { \
            _Pragma("unroll") \
            for (int k = 0; k < 7; k++) { \
                int idx = f2b_ + k * 64 + lane; \
                bool ok = idx < totF2; \
                pa[k] = ok ? pred2[idx] : make_float2(0.f, 0.f); \
                pb[k] = ok ? targ2[idx] : make_float2(0.f, 0.f); \
            } \
        } \
    } while (0)

    float val = 0.f;
    PREFETCH(tile0);

    // pipelined tile loop: ds_write(cur) -> prefetch(next) -> ds_read -> compute.
    // Wave-private LDS buffer + in-order same-wave DS ops: no barriers needed;
    // next tile's global loads fly during current tile's compute.
    #pragma unroll 1
    for (int t = 0; t < TILES; t++) {
        #pragma unroll
        for (int k = 0; k < 7; k++) {
            ldsP[k * 64 + lane] = pa[k];
            ldsT[k * 64 + lane] = pb[k];
        }
        if (t + 1 < TILES) PREFETCH(tile0 + t + 1);
        float af[14], bf[14];
        #pragma unroll
        for (int j = 0; j < 7; j++) {
            float2 va = ldsP[7 * lane + j];
            float2 vb = ldsT[7 * lane + j];
            af[2 * j] = va.x; af[2 * j + 1] = va.y;
            bf[2 * j] = vb.x; bf[2 * j + 1] = vb.y;
        }
        int e0 = (tile0 + t) * TILE_ELEMS + 2 * lane;
        if ((tile0 + t + 1) * TILE_ELEMS <= N) {       // wave-uniform full-tile fast path
            val += elem_loss(&af[0], &bf[0]);
            val += elem_loss(&af[7], &bf[7]);
        } else {
            if (e0 < N)     val += elem_loss(&af[0], &bf[0]);
            if (e0 + 1 < N) val += elem_loss(&af[7], &bf[7]);
        }
    }
    #undef PREFETCH

    // ---- block reduction -> per-block partial (no fences, no atomics) ----
    #pragma unroll
    for (int off = 32; off > 0; off >>= 1)
        val += __shfl_down(val, off, 64);
    __shared__ float wsum[WAVES];
    if (lane == 0) wsum[wid] = val;
    __syncthreads();
    if (threadIdx.x == 0) {
        float s = 0.f;
        #pragma unroll
        for (int q = 0; q < WAVES; q++) s += wsum[q];
        partial[blockIdx.x] = s;
    }
}

__global__ __launch_bounds__(256) void iou3d_finalize_kernel(
    const float* __restrict__ partial, float* __restrict__ out, int nb, int N)
{
    float s = 0.f;
    for (int i = threadIdx.x; i < nb; i += 256) s += partial[i];
    #pragma unroll
    for (int off = 32; off > 0; off >>= 1)
        s += __shfl_down(s, off, 64);
    __shared__ float ws[4];
    int lane = threadIdx.x & 63, wid = threadIdx.x >> 6;
    if (lane == 0) ws[wid] = s;
    __syncthreads();
    if (threadIdx.x == 0) {
        float t = ws[0] + ws[1] + ws[2] + ws[3];
        out[0] = (float)((double)t / (double)N);
    }
}

extern "C" void kernel_launch(void* const* d_in, const int* in_sizes, int n_in,
                              void* d_out, int out_size, void* d_ws, size_t ws_size,
                              hipStream_t stream) {
    const float* pred   = (const float*)d_in[0];
    const float* target = (const float*)d_in[1];
    int N = in_sizes[0] / 7;
    float* partial = (float*)d_ws;

    long tiles = ((long)N + TILE_ELEMS - 1) / TILE_ELEMS;
    long waves = (tiles + TILES - 1) / TILES;
    int grid = (int)((waves + WAVES - 1) / WAVES);

    iou3d_loss_kernel<<<grid, 256, 0, stream>>>(pred, target, partial, N);
    iou3d_finalize_kernel<<<1, 256, 0, stream>>>(partial, (float*)d_out, grid, N);
}

// Round 15
// 18.818 us; speedup vs baseline: 1.7665x; 1.0101x over previous
//
#include <hip/hip_runtime.h>
#include <math.h>

__device__ __forceinline__ float frcp(float x) { return __builtin_amdgcn_rcpf(x); }

// Exact area of CCW polygon ∩ axis-aligned box [-hw,hw]x[-hh,hh] via the
// per-edge coverage identity (validated R5-R14, absmax 0 vs jax reference):
//   Area = sum_e sigma_e * ( ∫ clamp(y_e(x), Y0, Y1) dx - Y0 * w_e ),
// integral over the edge's x-range clipped to the box's x-slab.
__device__ __forceinline__ float edge_area(float px, float py, float qx, float qy,
                                           float hw, float hh) {
    const float Y0 = -hh, Y1 = hh;
    float dx = qx - px, dy = qy - py;
    float lo = fmaxf(fminf(px, qx), -hw);
    float hi = fminf(fmaxf(px, qx),  hw);
    float w  = hi - lo;
    float dys = (fabsf(dy) > 1e-20f) ? dy : ((dy >= 0.f) ? 1e-20f : -1e-20f);
    float dxs = (fabsf(dx) > 1e-20f) ? dx : ((dx >= 0.f) ? 1e-20f : -1e-20f);
    float xdy = dx * frcp(dys);
    float m   = dy * frcp(dxs);
    float xa = fmaf(Y0 - py, xdy, px);
    float xb = fmaf(Y1 - py, xdy, px);
    float s0 = fminf(xa, xb), s1 = fmaxf(xa, xb);
    float u0 = fminf(fmaxf(s0, lo), hi);
    float u1 = fminf(fmaxf(s1, lo), hi);
    float yu0 = fmaf(m, u0 - px, py);
    float yu1 = fmaf(m, u1 - px, py);
    yu0 = fminf(fmaxf(yu0, Y0), Y1);
    yu1 = fminf(fmaxf(yu1, Y0), Y1);
    bool mpos = (dy >= 0.f) == (dx >= 0.f);
    float YL = mpos ? Y0 : Y1;
    float YR = mpos ? Y1 : Y0;
    float integral = YL * (u0 - lo)
                   + 0.5f * (yu0 + yu1) * (u1 - u0)
                   + YR * (hi - u1);
    float contrib = integral - Y0 * w;
    float res = (dx > 0.f) ? -contrib : contrib;
    return (w > 0.f) ? res : 0.f;
}

// one element: b1/b2 are 7 floats each -> 1 - iou3d
__device__ __forceinline__ float elem_loss(const float b1[7], const float b2[7]) {
    float x1 = b1[0], y1 = b1[1], z1 = b1[2], w1 = b1[3], h1 = b1[4], dz1 = b1[5], a1 = b1[6];
    float x2 = b2[0], y2 = b2[1], z2 = b2[2], w2 = b2[3], h2 = b2[4], dz2 = b2[5], a2 = b2[6];

    float zo = fmaxf(fminf(z1 + 0.5f * dz1, z2 + 0.5f * dz2)
                   - fmaxf(z1 - 0.5f * dz1, z2 - 0.5f * dz2), 0.0f);
    float vol1 = w1 * h1 * dz1;
    float vol2 = w2 * h2 * dz2;

    float sa = __sinf(a2), ca = __cosf(a2);
    float dxc = x1 - x2, dyc = y1 - y2;
    float tx =  dxc * ca + dyc * sa;
    float ty = -dxc * sa + dyc * ca;
    float ad = a1 - a2;
    float sd = __sinf(ad), cd = __cosf(ad);
    float hw1 = 0.5f * w1, hh1 = 0.5f * h1;
    float hw2 = 0.5f * w2, hh2 = 0.5f * h2;
    float ex = hw1 * cd, ey = hw1 * sd;
    float fx = -hh1 * sd, fy = hh1 * cd;
    float q0x = tx + ex + fx, q0y = ty + ey + fy;
    float q1x = tx - ex + fx, q1y = ty - ey + fy;
    float q2x = tx - ex - fx, q2y = ty - ey - fy;
    float q3x = tx + ex - fx, q3y = ty + ey - fy;

    float area = edge_area(q0x, q0y, q1x, q1y, hw2, hh2)
               + edge_area(q1x, q1y, q2x, q2y, hw2, hh2)
               + edge_area(q2x, q2y, q3x, q3y, hw2, hh2)
               + edge_area(q3x, q3y, q0x, q0y, hw2, hh2);
    area = fabsf(area);

    float inter3d = area * zo;
    float union3d = vol1 + vol2 - inter3d;
    return 1.0f - inter3d * frcp(union3d);   // fast rcp: ~1e-7 rel err vs 2e-2 threshold
}

#define WAVES 4        // waves per 256-thread block
#define TILES 2        // tiles per wave: pipeline depth 1 + 2x the TLP of TILES=4
#define TILE_ELEMS 128 // elems per tile (2 per lane)

// NOTE: assumes N even (N=1e6 here), so N*7/2 is exact in float2 units.

__global__ __launch_bounds__(256) void iou3d_loss_kernel(
    const float* __restrict__ pred, const float* __restrict__ target,
    float* __restrict__ partial, int N)
{
    __shared__ float lds[WAVES][1792];   // per-wave: 896 f32 pred + 896 f32 target
    const int lane = threadIdx.x & 63;
    const int wid  = threadIdx.x >> 6;
    const int gw   = blockIdx.x * WAVES + wid;     // global wave id
    const int tile0 = gw * TILES;
    const int totF2 = (N * 7) >> 1;                // float2 count (N even)

    const float2* pred2 = (const float2*)pred;
    const float2* targ2 = (const float2*)target;
    float2* ldsP = (float2*)&lds[wid][0];
    float2* ldsT = (float2*)&lds[wid][896];

    float2 pa[7], pb[7];

    // guarded/unguarded prefetch of tile TIDX into pa/pb
    #define PREFETCH(TIDX) do { \
        const int f2b_ = (TIDX) * 448; \
        if (((TIDX) + 1) * TILE_ELEMS <= N) { \
            _Pragma("unroll") \
            for (int k = 0; k < 7; k++) { \
                int idx = f2b_ + k * 64 + lane; \
                pa[k] = pred2[idx]; pb[k] = targ2[idx]; \
            } \
        } else { \
            _Pragma("unroll") \
            for (int k = 0; k < 7; k++) { \
                int idx = f2b_ + k * 64 + lane; \
                bool ok = idx < totF2; \
                pa[k] = ok ? pred2[idx] : make_float2(0.f, 0.f); \
                pb[k] = ok ? targ2[idx] : make_float2(0.f, 0.f); \
            } \
        } \
    } while (0)

    float val = 0.f;
    PREFETCH(tile0);

    // pipelined tile loop: ds_write(cur) -> prefetch(next) -> ds_read -> compute.
    // Wave-private LDS buffer + in-order same-wave DS ops: no barriers needed;
    // next tile's global loads fly during current tile's compute.
    #pragma unroll 1
    for (int t = 0; t < TILES; t++) {
        #pragma unroll
        for (int k = 0; k < 7; k++) {
            ldsP[k * 64 + lane] = pa[k];
            ldsT[k * 64 + lane] = pb[k];
        }
        if (t + 1 < TILES) PREFETCH(tile0 + t + 1);
        float af[14], bf[14];
        #pragma unroll
        for (int j = 0; j < 7; j++) {
            float2 va = ldsP[7 * lane + j];
            float2 vb = ldsT[7 * lane + j];
            af[2 * j] = va.x; af[2 * j + 1] = va.y;
            bf[2 * j] = vb.x; bf[2 * j + 1] = vb.y;
        }
        int e0 = (tile0 + t) * TILE_ELEMS + 2 * lane;
        if ((tile0 + t + 1) * TILE_ELEMS <= N) {       // wave-uniform full-tile fast path
            val += elem_loss(&af[0], &bf[0]);
            val += elem_loss(&af[7], &bf[7]);
        } else {
            if (e0 < N)     val += elem_loss(&af[0], &bf[0]);
            if (e0 + 1 < N) val += elem_loss(&af[7], &bf[7]);
        }
    }
    #undef PREFETCH

    // ---- block reduction -> per-block partial (no fences, no atomics) ----
    #pragma unroll
    for (int off = 32; off > 0; off >>= 1)
        val += __shfl_down(val, off, 64);
    __shared__ float wsum[WAVES];
    if (lane == 0) wsum[wid] = val;
    __syncthreads();
    if (threadIdx.x == 0) {
        float s = 0.f;
        #pragma unroll
        for (int q = 0; q < WAVES; q++) s += wsum[q];
        partial[blockIdx.x] = s;
    }
}

__global__ __launch_bounds__(256) void iou3d_finalize_kernel(
    const float* __restrict__ partial, float* __restrict__ out, int nb, int N)
{
    float s = 0.f;
    for (int i = threadIdx.x; i < nb; i += 256) s += partial[i];
    #pragma unroll
    for (int off = 32; off > 0; off >>= 1)
        s += __shfl_down(s, off, 64);
    __shared__ float ws[4];
    int lane = threadIdx.x & 63, wid = threadIdx.x >> 6;
    if (lane == 0) ws[wid] = s;
    __syncthreads();
    if (threadIdx.x == 0) {
        float t = ws[0] + ws[1] + ws[2] + ws[3];
        out[0] = (float)((double)t / (double)N);
    }
}

extern "C" void kernel_launch(void* const* d_in, const int* in_sizes, int n_in,
                              void* d_out, int out_size, void* d_ws, size_t ws_size,
                              hipStream_t stream) {
    const float* pred   = (const float*)d_in[0];
    const float* target = (const float*)d_in[1];
    int N = in_sizes[0] / 7;
    float* partial = (float*)d_ws;

    long tiles = ((long)N + TILE_ELEMS - 1) / TILE_ELEMS;
    long waves = (tiles + TILES - 1) / TILES;
    int grid = (int)((waves + WAVES - 1) / WAVES);

    iou3d_loss_kernel<<<grid, 256, 0, stream>>>(pred, target, partial, N);
    iou3d_finalize_kernel<<<1, 256, 0, stream>>>(partial, (float*)d_out, grid, N);
}